// Round 1
// baseline (252.632 us; speedup 1.0000x reference)
//
#include <hip/hip_runtime.h>
#include <hip/hip_bf16.h>
#include <math.h>

#define N_NODES 10000
#define N_EDGES 100000
#define NCH 64
#define NSPEC 10

static __device__ __forceinline__ float silu_f(float x){ return x / (1.0f + __expf(-x)); }

// ---------- CSR build ----------
__global__ void k_count(const int* __restrict__ recv, int* __restrict__ cnt){
  int i = blockIdx.x*blockDim.x + threadIdx.x;
  if (i < N_EDGES) atomicAdd(&cnt[recv[i]], 1);
}

__global__ void k_scan(int* __restrict__ cnt_cursor, int* __restrict__ starts){
  __shared__ int sd[1024];
  int tid = threadIdx.x;
  int running = 0;
  for (int base = 0; base < N_NODES; base += 1024){
    int i = base + tid;
    int v = (i < N_NODES) ? cnt_cursor[i] : 0;
    sd[tid] = v;
    __syncthreads();
    for (int off = 1; off < 1024; off <<= 1){
      int t = (tid >= off) ? sd[tid - off] : 0;
      __syncthreads();
      sd[tid] += t;
      __syncthreads();
    }
    int excl = running + sd[tid] - v;
    if (i < N_NODES){ starts[i] = excl; cnt_cursor[i] = excl; }
    int tot = sd[1023];
    __syncthreads();
    running += tot;
  }
  if (tid == 0) starts[N_NODES] = running;
}

__global__ void k_fill(const int* __restrict__ recv, int* __restrict__ cursor, int* __restrict__ elist){
  int i = blockIdx.x*blockDim.x + threadIdx.x;
  if (i < N_EDGES){ int pos = atomicAdd(&cursor[recv[i]], 1); elist[pos] = i; }
}

// ---------- weight transposes: T[s][d][c] = W[s][c][d] ----------
__global__ void k_trans(const float* __restrict__ sel, const float* __restrict__ resw,
                        float* __restrict__ selT, float* __restrict__ resT){
  int i = blockIdx.x*blockDim.x + threadIdx.x;          // 10*4096
  int s = i >> 12, r = i & 4095, d = r >> 6, c = r & 63;
  int src = s*4096 + c*64 + d;
  selT[i] = sel[src];
  resT[i] = resw[src];
}

// ---------- h1 = embed[species] @ l1_lin_up ----------
__global__ void k_h1(const int* __restrict__ species, const float* __restrict__ embedW,
                     const float* __restrict__ linup, float* __restrict__ h1){
  int w = (blockIdx.x*blockDim.x + threadIdx.x) >> 6;
  int lane = threadIdx.x & 63;
  if (w >= N_NODES) return;
  int sp = __builtin_amdgcn_readfirstlane(species[w]);
  const float* x0 = embedW + sp*NCH;
  float acc = 0.f;
  #pragma unroll
  for (int d = 0; d < NCH; d++) acc += x0[d] * linup[d*NCH + lane];
  h1[w*NCH + lane] = acc;
}

// ---------- per-edge: geometry + bessel + both radial hidden layers ----------
__global__ void k_edge(const float* __restrict__ ev,
                       const float* __restrict__ rW1a, const float* __restrict__ rW1b,
                       float* __restrict__ hid1, float* __restrict__ hid2){
  int e = (blockIdx.x*blockDim.x + threadIdx.x) >> 6;
  int lane = threadIdx.x & 63;
  if (e >= N_EDGES) return;
  float ex = ev[e*3+0], ey = ev[e*3+1], ez = ev[e*3+2];
  float r = sqrtf(ex*ex + ey*ey + ez*ez + 1e-12f);
  float u = r * 0.2f;                     // r / R_MAX
  float env = 0.f;
  if (u < 1.f){ float om = 1.f - u; env = om*om*(1.f + 2.f*u); }
  float pref = 0.6324555320336759f / r * env;   // sqrt(2/5)
  float rad[8];
  #pragma unroll
  for (int b = 0; b < 8; b++)
    rad[b] = pref * __sinf((float)(b+1) * 3.14159265358979f * u);
  float a1 = 0.f, a2 = 0.f;
  #pragma unroll
  for (int b = 0; b < 8; b++){
    a1 += rad[b] * rW1a[b*64 + lane];
    a2 += rad[b] * rW1b[b*64 + lane];
  }
  hid1[(size_t)e*64 + lane] = silu_f(a1);
  hid2[(size_t)e*64 + lane] = silu_f(a2);
}

// ---------- pass-1 gather + node transforms ----------
__global__ __launch_bounds__(256) void k_node1(
  const float* __restrict__ ev, const int* __restrict__ senders,
  const int* __restrict__ species,
  const int* __restrict__ starts, const int* __restrict__ elist,
  const float* __restrict__ hid1, const float* __restrict__ h1,
  const float* __restrict__ rW2a,
  const float* __restrict__ selT,
  const float* __restrict__ pw, const float* __restrict__ uwv,
  const float* __restrict__ row,
  const float* __restrict__ linup2, const float* __restrict__ resT,
  float* __restrict__ out,
  float* __restrict__ h2o, float* __restrict__ outvo, float* __restrict__ reso)
{
  int lane = threadIdx.x & 63;
  int wslot = threadIdx.x >> 6;
  int n = blockIdx.x*4 + wslot;
  __shared__ float4 sacc[4][64];

  // per-lane weight slice of l1_rW2: columns 4c (k=0) and 4c+1 (k=1..3)
  float2 wa[64];
  #pragma unroll
  for (int h = 0; h < 64; h++)
    wa[h] = *reinterpret_cast<const float2*>(rW2a + h*256 + 4*lane);

  bool active = (n < N_NODES);
  int s0 = 0, s1 = 0, sp = 0;
  if (active){ s0 = starts[n]; s1 = starts[n+1]; sp = species[n]; }
  s0 = __builtin_amdgcn_readfirstlane(s0);
  s1 = __builtin_amdgcn_readfirstlane(s1);
  sp = __builtin_amdgcn_readfirstlane(sp);

  float acc0 = 0.f, acc1 = 0.f, acc2 = 0.f, acc3 = 0.f;
  for (int ii = s0; ii < s1; ii++){
    int e   = __builtin_amdgcn_readfirstlane(elist[ii]);
    int snd = __builtin_amdgcn_readfirstlane(senders[e]);
    float ex = ev[e*3+0], ey = ev[e*3+1], ez = ev[e*3+2];
    float rinv = 1.0f / sqrtf(ex*ex + ey*ey + ez*ez + 1e-12f);
    float c1 = 1.7320508075688772f * rinv;     // sqrt(3)/r
    float shx = c1*ex, shy = c1*ey, shz = c1*ez;
    float h1s = h1[snd*64 + lane];
    const float4* hp = reinterpret_cast<const float4*>(hid1 + (size_t)e*64);
    float rw0 = 0.f, rw1 = 0.f;
    #pragma unroll
    for (int i = 0; i < 16; i++){
      float4 hv = hp[i];
      rw0 += hv.x*wa[4*i+0].x; rw1 += hv.x*wa[4*i+0].y;
      rw0 += hv.y*wa[4*i+1].x; rw1 += hv.y*wa[4*i+1].y;
      rw0 += hv.z*wa[4*i+2].x; rw1 += hv.z*wa[4*i+2].y;
      rw0 += hv.w*wa[4*i+3].x; rw1 += hv.w*wa[4*i+3].y;
    }
    float m = rw1 * h1s;
    acc0 += rw0 * h1s;
    acc1 += m * shx; acc2 += m * shy; acc3 += m * shz;
  }
  acc0 *= 0.1f; acc1 *= 0.1f; acc2 *= 0.1f; acc3 *= 0.1f;   // / AVG_NEIGH

  sacc[wslot][lane] = make_float4(acc0, acc1, acc2, acc3);
  asm volatile("s_waitcnt lgkmcnt(0)" ::: "memory");

  // feats[c,k] = sum_d selW[c,d] * agg[d,k]   (selT[d][c])
  float f0 = 0.f, f1 = 0.f, f2 = 0.f, f3 = 0.f;
  const float* selp = selT + sp*4096;
  #pragma unroll 8
  for (int d = 0; d < 64; d++){
    float4 a = sacc[wslot][d];
    float wv = selp[d*64 + lane];
    f0 += wv*a.x; f1 += wv*a.y; f2 += wv*a.z; f3 += wv*a.w;
  }

  float s = f0;
  const float* pwp = pw  + sp*192;
  const float* uwp = uwv + sp*192;
  float pw0 = pwp[lane], pw1 = pwp[64+lane], pw2 = pwp[128+lane];
  float uw0 = uwp[lane], uw1 = uwp[64+lane], uw2 = uwp[128+lane];
  float ss = s*s;
  float o0  = pw0*s + pw1*ss + pw2*ss*s;
  float uco = uw0 + uw1*s + uw2*ss;
  float ov0 = uco*f1, ov1 = uco*f2, ov2 = uco*f3;

  // ro1 = sum_c o0[c] * row[c]
  float rv = o0 * row[lane];
  #pragma unroll
  for (int off = 32; off >= 1; off >>= 1) rv += __shfl_xor(rv, off, 64);

  // stage o0 for h2/res (reuse sacc memory)
  float* so = reinterpret_cast<float*>(&sacc[wslot][0]);
  asm volatile("s_waitcnt lgkmcnt(0)" ::: "memory");
  so[lane] = o0;
  asm volatile("s_waitcnt lgkmcnt(0)" ::: "memory");

  float hh = 0.f, rr = 0.f;
  const float* resp = resT + sp*4096;
  #pragma unroll 8
  for (int d = 0; d < 64; d++){
    float od = so[d];
    hh += od * linup2[d*64 + lane];
    rr += od * resp[d*64 + lane];
  }

  if (active){
    if (lane == 0) out[n*2 + 0] = rv;
    h2o[n*64 + lane]  = hh;
    reso[n*64 + lane] = rr;
    outvo[n*192 +       lane] = ov0;
    outvo[n*192 +  64 + lane] = ov1;
    outvo[n*192 + 128 + lane] = ov2;
  }
}

// ---------- pass-2 gather + readout ----------
__global__ __launch_bounds__(256) void k_node2(
  const float* __restrict__ ev, const int* __restrict__ senders,
  const int* __restrict__ species,
  const int* __restrict__ starts, const int* __restrict__ elist,
  const float* __restrict__ hid2,
  const float* __restrict__ rW2b,
  const float* __restrict__ h2o, const float* __restrict__ outvo,
  const float* __restrict__ reso,
  const float* __restrict__ pw2,
  const float* __restrict__ roW1, const float* __restrict__ roW2,
  float* __restrict__ out)
{
  int lane = threadIdx.x & 63;
  int wslot = threadIdx.x >> 6;
  int n = blockIdx.x*4 + wslot;
  __shared__ float sout[4][64];

  float wb[64];
  #pragma unroll
  for (int h = 0; h < 64; h++) wb[h] = rW2b[h*256 + 4*lane];

  bool active = (n < N_NODES);
  int s0 = 0, s1 = 0, sp = 0;
  if (active){ s0 = starts[n]; s1 = starts[n+1]; sp = species[n]; }
  s0 = __builtin_amdgcn_readfirstlane(s0);
  s1 = __builtin_amdgcn_readfirstlane(s1);
  sp = __builtin_amdgcn_readfirstlane(sp);

  float acc = 0.f;
  for (int ii = s0; ii < s1; ii++){
    int e   = __builtin_amdgcn_readfirstlane(elist[ii]);
    int snd = __builtin_amdgcn_readfirstlane(senders[e]);
    float ex = ev[e*3+0], ey = ev[e*3+1], ez = ev[e*3+2];
    float rinv = 1.0f / sqrtf(ex*ex + ey*ey + ez*ez + 1e-12f);
    float ux = ex*rinv, uy = ey*rinv, uz = ez*rinv;
    const float4* hp = reinterpret_cast<const float4*>(hid2 + (size_t)e*64);
    float rw = 0.f;
    #pragma unroll
    for (int i = 0; i < 16; i++){
      float4 hv = hp[i];
      rw += hv.x*wb[4*i+0] + hv.y*wb[4*i+1] + hv.z*wb[4*i+2] + hv.w*wb[4*i+3];
    }
    float h2s = h2o[snd*64 + lane];
    float edt = outvo[snd*192 + lane]*ux + outvo[snd*192 + 64 + lane]*uy
              + outvo[snd*192 + 128 + lane]*uz;
    acc += rw * (h2s + edt);
  }
  float s2 = acc * 0.1f;
  const float* p2 = pw2 + sp*192;
  float q0 = p2[lane], q1 = p2[64+lane], q2 = p2[128+lane];
  float s2s = s2*s2;
  float o2 = q0*s2 + q1*s2s + q2*s2s*s2 + (active ? reso[n*64 + lane] : 0.f);

  sout[wslot][lane] = o2;
  asm volatile("s_waitcnt lgkmcnt(0)" ::: "memory");

  // ro2 = silu(out2 @ roW1) @ roW2 : lane -> (j = lane&15, group g = lane>>4)
  int j = lane & 15, g = lane >> 4;
  float qp = 0.f;
  #pragma unroll
  for (int t = 0; t < 16; t++){
    int c = g*16 + t;
    qp += sout[wslot][c] * roW1[c*16 + j];
  }
  qp += __shfl_xor(qp, 16, 64);
  qp += __shfl_xor(qp, 32, 64);
  float sil = qp / (1.f + __expf(-qp));
  float contrib = sil * roW2[j];
  contrib += __shfl_xor(contrib, 1, 64);
  contrib += __shfl_xor(contrib, 2, 64);
  contrib += __shfl_xor(contrib, 4, 64);
  contrib += __shfl_xor(contrib, 8, 64);
  if (active && lane == 0) out[n*2 + 1] = contrib;
}

extern "C" void kernel_launch(void* const* d_in, const int* in_sizes, int n_in,
                              void* d_out, int out_size, void* d_ws, size_t ws_size,
                              hipStream_t stream)
{
  const float* ev     = (const float*)d_in[0];
  const int*   spec   = (const int*)  d_in[1];
  const int*   send   = (const int*)  d_in[2];
  const int*   recv   = (const int*)  d_in[3];
  const float* embedW = (const float*)d_in[4];
  const float* l1_lin = (const float*)d_in[5];
  const float* l1_rW1 = (const float*)d_in[6];
  const float* l1_rW2 = (const float*)d_in[7];
  const float* l1_sel = (const float*)d_in[8];
  const float* l1_pw  = (const float*)d_in[9];
  const float* l1_uw  = (const float*)d_in[10];
  const float* l1_row = (const float*)d_in[11];
  const float* l2_lin = (const float*)d_in[12];
  const float* l2_rW1 = (const float*)d_in[13];
  const float* l2_rW2 = (const float*)d_in[14];
  const float* l2_res = (const float*)d_in[15];
  const float* l2_pw  = (const float*)d_in[16];
  const float* l2_roW1= (const float*)d_in[17];
  const float* l2_roW2= (const float*)d_in[18];
  float* out = (float*)d_out;

  char* w = (char*)d_ws;
  float* hid1 = (float*)w;  w += (size_t)N_EDGES*64*4;
  float* hid2 = (float*)w;  w += (size_t)N_EDGES*64*4;
  float* h1   = (float*)w;  w += (size_t)N_NODES*64*4;
  float* h2o  = (float*)w;  w += (size_t)N_NODES*64*4;
  float* outvo= (float*)w;  w += (size_t)N_NODES*192*4;
  float* reso = (float*)w;  w += (size_t)N_NODES*64*4;
  float* selT = (float*)w;  w += (size_t)NSPEC*4096*4;
  float* resT = (float*)w;  w += (size_t)NSPEC*4096*4;
  int* starts = (int*)w;    w += (size_t)(N_NODES+1)*4;
  int* cursor = (int*)w;    w += (size_t)N_NODES*4;
  int* elist  = (int*)w;    w += (size_t)N_EDGES*4;

  hipMemsetAsync(cursor, 0, N_NODES*sizeof(int), stream);
  k_count<<<(N_EDGES+255)/256, 256, 0, stream>>>(recv, cursor);
  k_scan <<<1, 1024, 0, stream>>>(cursor, starts);
  k_fill <<<(N_EDGES+255)/256, 256, 0, stream>>>(recv, cursor, elist);
  k_trans<<<(NSPEC*4096)/256, 256, 0, stream>>>(l1_sel, l2_res, selT, resT);
  k_h1   <<<(N_NODES*64)/256, 256, 0, stream>>>(spec, embedW, l1_lin, h1);
  k_edge <<<(N_EDGES*64)/256, 256, 0, stream>>>(ev, l1_rW1, l2_rW1, hid1, hid2);
  k_node1<<<(N_NODES+3)/4, 256, 0, stream>>>(ev, send, spec, starts, elist, hid1, h1,
        l1_rW2, selT, l1_pw, l1_uw, l1_row, l2_lin, resT, out, h2o, outvo, reso);
  k_node2<<<(N_NODES+3)/4, 256, 0, stream>>>(ev, send, spec, starts, elist, hid2,
        l2_rW2, h2o, outvo, reso, l2_pw, l2_roW1, l2_roW2, out);
}